// Round 2
// baseline (450.859 us; speedup 1.0000x reference)
//
#include <hip/hip_runtime.h>
#include <stdint.h>

// MegatronAttention: B=2, S=2048, H=2048, NH=16, DH=128.
// KEY INSIGHT: reference einsum 'bhqk,bhkd->bhkd' sums over q ->
//   values[b,h,k,d] = colsum_q(probs)[b,h,k] * v[b,h,k,d].
// Pipeline: convert->bf16, QKV GEMM (scatter epilogue, Q pre-scaled by
// 1/sqrt(d)*log2e), l-pass (row sums of exp2), cs-pass (weighted col sums,
// fused V scaling), output GEMM.
// R2: attn passes: hoist loop-invariant MFMA fragments to registers (halves
// LDS reads), double-buffer the streamed tile in the freed 32 KB (hides
// staging latency), exp2f instead of mul+__expf.

typedef __bf16 bf16_t;
typedef __bf16 bf16x8v __attribute__((ext_vector_type(8)));
typedef __bf16 bf16x4v __attribute__((ext_vector_type(4)));
typedef float  f32x4v  __attribute__((ext_vector_type(4)));

#define DEVINL __device__ __forceinline__

// async global->LDS DMA, 16B per lane. LDS dest is wave-uniform base;
// HW writes lane i's data at base + i*16.
DEVINL void gll16(const bf16_t* g, void* lds_wave_uniform_base) {
    __builtin_amdgcn_global_load_lds(
        (__attribute__((address_space(1))) void*)g,
        (__attribute__((address_space(3))) void*)lds_wave_uniform_base,
        16, 0, 0);
}

// ---------------------------------------------------------------- converts
__global__ void conv_x_k(const float* __restrict__ in, bf16_t* __restrict__ out) {
    size_t i = ((size_t)blockIdx.x * 256 + threadIdx.x) * 4;
    float4 v = *reinterpret_cast<const float4*>(in + i);
    bf16x4v o;
    o[0] = (__bf16)v.x; o[1] = (__bf16)v.y; o[2] = (__bf16)v.z; o[3] = (__bf16)v.w;
    *reinterpret_cast<bf16x4v*>(out + i) = o;
}

// out[n][k] = (bf16) in[k][n]   (in: K x N fp32, out: N x K bf16)
__global__ void conv_wT_k(const float* __restrict__ in, bf16_t* __restrict__ out,
                          int K, int N) {
    __shared__ float t[32][33];
    int n0 = blockIdx.x * 32, k0 = blockIdx.y * 32;
    int tx = threadIdx.x & 31, ty = threadIdx.x >> 5;   // ty in 0..7
#pragma unroll
    for (int i = 0; i < 32; i += 8)
        t[ty + i][tx] = in[(size_t)(k0 + ty + i) * N + n0 + tx];
    __syncthreads();
#pragma unroll
    for (int i = 0; i < 32; i += 8)
        out[(size_t)(n0 + ty + i) * K + k0 + tx] = (__bf16)t[tx][ty + i];
}

// ---------------------------------------------------------------- GEMM
// C[M,N] = A[M,K] @ B[N,K]^T, bf16 in, fp32 acc. 128x128 tile, BK=32,
// 256 threads (4 waves, 2x2 of 64x64), 16x16x32 MFMA.
// LDS staging via global_load_lds w=16 with XOR swizzle.
// MODE 0: scatter-write QKV (Q/K head-contig [bh][s][d], V token-major),
//         Q pre-scaled by 1/sqrt(128)*log2(e) for exp2-based softmax.
// MODE 1: plain fp32 store to out[m*N+n].
template<int MODE, int N, int K>
__launch_bounds__(256, 2)
__global__ void gemm_bt_k(const bf16_t* __restrict__ A, const bf16_t* __restrict__ Bm,
                          float* __restrict__ outF,
                          bf16_t* __restrict__ Qb, bf16_t* __restrict__ Kb,
                          bf16_t* __restrict__ Vb)
{
    __shared__ __align__(16) bf16_t sA[512 * 8];   // 8 KiB
    __shared__ __align__(16) bf16_t sB[512 * 8];
    const int tid  = threadIdx.x;
    const int lane = tid & 63, wave = tid >> 6;
    const int quad = lane >> 4, l15 = lane & 15;
    const int rowBase = blockIdx.y * 128, colBase = blockIdx.x * 128;
    const int wr0 = (wave >> 1) * 64, wc0 = (wave & 1) * 64;

    const bf16_t* gA[2]; const bf16_t* gB[2]; uint32_t loff[2];
#pragma unroll
    for (int r = 0; r < 2; ++r) {
        int s = r * 256 + wave * 64 + lane;
        int row = s >> 2, j = s & 3;
        int cc = j ^ ((row >> 1) & 3);
        gA[r] = A  + (size_t)(rowBase + row) * K + cc * 8;
        gB[r] = Bm + (size_t)(colBase + row) * K + cc * 8;
        loff[r] = (uint32_t)(r * 256 + wave * 64) * 16;
    }
    int aoff[4], boff[4];
#pragma unroll
    for (int t = 0; t < 4; ++t) {
        int m = wr0 + t * 16 + l15;
        aoff[t] = (m * 4 + (quad ^ ((m >> 1) & 3))) * 8;
        int n = wc0 + t * 16 + l15;
        boff[t] = (n * 4 + (quad ^ ((n >> 1) & 3))) * 8;
    }

    f32x4v acc[4][4] = {};
    for (int kt = 0; kt < K / 32; ++kt) {
        __syncthreads();
#pragma unroll
        for (int r = 0; r < 2; ++r) {
            gll16(gA[r] + kt * 32, (char*)sA + loff[r]);
            gll16(gB[r] + kt * 32, (char*)sB + loff[r]);
        }
        __syncthreads();
        bf16x8v av[4], bv[4];
#pragma unroll
        for (int t = 0; t < 4; ++t) av[t] = *reinterpret_cast<const bf16x8v*>(sA + aoff[t]);
#pragma unroll
        for (int t = 0; t < 4; ++t) bv[t] = *reinterpret_cast<const bf16x8v*>(sB + boff[t]);
#pragma unroll
        for (int ti = 0; ti < 4; ++ti)
#pragma unroll
            for (int tj = 0; tj < 4; ++tj)
                acc[ti][tj] = __builtin_amdgcn_mfma_f32_16x16x32_bf16(
                                  av[ti], bv[tj], acc[ti][tj], 0, 0, 0);
    }

    constexpr float QS = 0.08838834764831845f * 1.44269504088896341f;
#pragma unroll
    for (int ti = 0; ti < 4; ++ti)
#pragma unroll
        for (int tj = 0; tj < 4; ++tj)
#pragma unroll
            for (int r = 0; r < 4; ++r) {
                int m = rowBase + wr0 + ti * 16 + quad * 4 + r;   // C row
                int n = colBase + wc0 + tj * 16 + l15;            // C col
                float v = acc[ti][tj][r];
                if constexpr (MODE == 0) {
                    int b = m >> 11, s = m & 2047;
                    int which = n >> 11, hd = n & 2047;           // uniform per block
                    if (which == 2) {
                        Vb[(size_t)m * 2048 + hd] = (__bf16)v;    // token-major
                    } else {
                        if (which == 0) v *= QS;                  // fold softmax scale
                        size_t idx = ((size_t)((b << 4) + (hd >> 7)) * 2048 + s) * 128
                                     + (hd & 127);
                        if (which == 0) Qb[idx] = (__bf16)v; else Kb[idx] = (__bf16)v;
                    }
                } else {
                    outF[(size_t)m * N + n] = v;
                }
            }
}

// ---------------------------------------------------------------- attention
// Both attn kernels: 128 resident rows (frags hoisted to registers) x 2048
// streamed rows (double-buffered 32 KB tiles) x d=128 per block.
// LDS: 2 x 32 KiB buffers = 64 KiB -> 2 blocks/CU.
// Swizzle: 16 chunks of 16B per 256B row, content chunk cc = j ^ (row&7).

__launch_bounds__(256, 2)
__global__ void attn_l_k(const bf16_t* __restrict__ Qb, const bf16_t* __restrict__ Kb,
                         float* __restrict__ rl)
{
    __shared__ __align__(16) bf16_t lds[2][2048 * 8];   // 2 x 32 KiB
    const int tid  = threadIdx.x;
    const int lane = tid & 63, wave = tid >> 6;
    const int quad = lane >> 4, l15 = lane & 15;
    const int qt = blockIdx.x, bh = blockIdx.y;
    const bf16_t* Qg = Qb + (size_t)bh * 2048 * 128 + (size_t)qt * 128 * 128;
    const bf16_t* Kg = Kb + (size_t)bh * 2048 * 128;
    const int wr0 = (wave >> 1) * 64, wc0 = (wave & 1) * 64;

    int srow[8], scc[8]; uint32_t soff[8];
#pragma unroll
    for (int r = 0; r < 8; ++r) {
        int s = r * 256 + wave * 64 + lane;
        srow[r] = s >> 4; int j = s & 15;
        scc[r] = j ^ (srow[r] & 7);
        soff[r] = (uint32_t)(r * 256 + wave * 64) * 16;
    }
    // stage resident Q tile into buf0
#pragma unroll
    for (int r = 0; r < 8; ++r)
        gll16(Qg + (size_t)srow[r] * 128 + scc[r] * 8, (char*)lds[0] + soff[r]);
    __syncthreads();
    // prefetch K tile 0 into buf1 (overlaps with Q frag hoisting)
#pragma unroll
    for (int r = 0; r < 8; ++r)
        gll16(Kg + (size_t)srow[r] * 128 + scc[r] * 8, (char*)lds[1] + soff[r]);
    // hoist Q fragments: invariant across the whole k sweep
    bf16x8v qf[4][4];   // [kb][ti]
#pragma unroll
    for (int kb = 0; kb < 4; ++kb)
#pragma unroll
        for (int t = 0; t < 4; ++t) {
            int m = wr0 + t * 16 + l15;
            qf[kb][t] = *reinterpret_cast<const bf16x8v*>(
                lds[0] + (m * 16 + ((kb * 4 + quad) ^ (m & 7))) * 8);
        }

    float lsum[4][4] = {};   // [ti][reg] per-lane partial row sums
    for (int nt = 0; nt < 16; ++nt) {
        __syncthreads();     // K[nt] staged; prior reads of other buf done
        const bf16_t* cb = lds[(nt & 1) ^ 1];
        if (nt < 15) {
            char* tgt = (char*)lds[nt & 1];
#pragma unroll
            for (int r = 0; r < 8; ++r)
                gll16(Kg + (size_t)((nt + 1) * 128 + srow[r]) * 128 + scc[r] * 8,
                      tgt + soff[r]);
        }
        f32x4v sc[4][4] = {};
#pragma unroll
        for (int kb = 0; kb < 4; ++kb) {
            bf16x8v bv[4];
            int ccq = kb * 4 + quad;
#pragma unroll
            for (int t = 0; t < 4; ++t) {
                int n = wc0 + t * 16 + l15;
                bv[t] = *reinterpret_cast<const bf16x8v*>(cb + (n * 16 + (ccq ^ (n & 7))) * 8);
            }
#pragma unroll
            for (int ti = 0; ti < 4; ++ti)
#pragma unroll
                for (int tj = 0; tj < 4; ++tj)
                    sc[ti][tj] = __builtin_amdgcn_mfma_f32_16x16x32_bf16(
                                     qf[kb][ti], bv[tj], sc[ti][tj], 0, 0, 0);
        }
#pragma unroll
        for (int ti = 0; ti < 4; ++ti)
#pragma unroll
            for (int r = 0; r < 4; ++r) {
                float e = 0.f;
#pragma unroll
                for (int tj = 0; tj < 4; ++tj) e += exp2f(sc[ti][tj][r]);
                lsum[ti][r] += e;
            }
    }
    __syncthreads();                      // all buffers dead; alias buf0
    float* l_sh = (float*)lds[0];
    if (tid < 128) l_sh[tid] = 0.f;
    __syncthreads();
#pragma unroll
    for (int ti = 0; ti < 4; ++ti)
#pragma unroll
        for (int r = 0; r < 4; ++r) {
            float v = lsum[ti][r];
            v += __shfl_xor(v, 1); v += __shfl_xor(v, 2);
            v += __shfl_xor(v, 4); v += __shfl_xor(v, 8);
            if (l15 == 0) atomicAdd(&l_sh[wr0 + ti * 16 + quad * 4 + r], v);
        }
    __syncthreads();
    if (tid < 128) rl[(size_t)bh * 2048 + qt * 128 + tid] = 1.0f / l_sh[tid];
}

__launch_bounds__(256, 2)
__global__ void attn_cs_k(const bf16_t* __restrict__ Qb, const bf16_t* __restrict__ Kb,
                          const float* __restrict__ rl, bf16_t* __restrict__ Vb)
{
    __shared__ __align__(16) bf16_t lds[2][2048 * 8];   // 2 x 32 KiB
    const int tid  = threadIdx.x;
    const int lane = tid & 63, wave = tid >> 6;
    const int quad = lane >> 4, l15 = lane & 15;
    const int kt = blockIdx.x, bh = blockIdx.y;
    const bf16_t* Qg = Qb + (size_t)bh * 2048 * 128;
    const bf16_t* Kg = Kb + (size_t)bh * 2048 * 128 + (size_t)kt * 128 * 128;
    const float* rlg = rl + (size_t)bh * 2048;
    const int wr0 = (wave >> 1) * 64, wc0 = (wave & 1) * 64;

    int srow[8], scc[8]; uint32_t soff[8];
#pragma unroll
    for (int r = 0; r < 8; ++r) {
        int s = r * 256 + wave * 64 + lane;
        srow[r] = s >> 4; int j = s & 15;
        scc[r] = j ^ (srow[r] & 7);
        soff[r] = (uint32_t)(r * 256 + wave * 64) * 16;
    }
    // stage resident K tile into buf0
#pragma unroll
    for (int r = 0; r < 8; ++r)
        gll16(Kg + (size_t)srow[r] * 128 + scc[r] * 8, (char*)lds[0] + soff[r]);
    __syncthreads();
    // prefetch Q tile 0 into buf1
#pragma unroll
    for (int r = 0; r < 8; ++r)
        gll16(Qg + (size_t)srow[r] * 128 + scc[r] * 8, (char*)lds[1] + soff[r]);
    // hoist K fragments (B operand): invariant across the whole q sweep
    bf16x8v kf[4][4];   // [kb][tj]
#pragma unroll
    for (int kb = 0; kb < 4; ++kb)
#pragma unroll
        for (int t = 0; t < 4; ++t) {
            int n = wc0 + t * 16 + l15;
            kf[kb][t] = *reinterpret_cast<const bf16x8v*>(
                lds[0] + (n * 16 + ((kb * 4 + quad) ^ (n & 7))) * 8);
        }

    float csum[4] = {};             // [tj] per-lane partial col sums
    for (int qt = 0; qt < 16; ++qt) {
        __syncthreads();
        const bf16_t* cb = lds[(qt & 1) ^ 1];
        if (qt < 15) {
            char* tgt = (char*)lds[qt & 1];
#pragma unroll
            for (int r = 0; r < 8; ++r)
                gll16(Qg + (size_t)((qt + 1) * 128 + srow[r]) * 128 + scc[r] * 8,
                      tgt + soff[r]);
        }
        f32x4v sc[4][4] = {};
#pragma unroll
        for (int kb = 0; kb < 4; ++kb) {
            bf16x8v av[4];
            int ccq = kb * 4 + quad;
#pragma unroll
            for (int t = 0; t < 4; ++t) {
                int m = wr0 + t * 16 + l15;          // q row (A operand)
                av[t] = *reinterpret_cast<const bf16x8v*>(cb + (m * 16 + (ccq ^ (m & 7))) * 8);
            }
#pragma unroll
            for (int ti = 0; ti < 4; ++ti)
#pragma unroll
                for (int tj = 0; tj < 4; ++tj)
                    sc[ti][tj] = __builtin_amdgcn_mfma_f32_16x16x32_bf16(
                                     av[ti], kf[kb][tj], sc[ti][tj], 0, 0, 0);
        }
#pragma unroll
        for (int ti = 0; ti < 4; ++ti) {
            f32x4v rlv = *reinterpret_cast<const f32x4v*>(
                rlg + qt * 128 + wr0 + ti * 16 + quad * 4);
#pragma unroll
            for (int r = 0; r < 4; ++r)
#pragma unroll
                for (int tj = 0; tj < 4; ++tj)
                    csum[tj] += exp2f(sc[ti][tj][r]) * rlv[r];
        }
    }
    __syncthreads();                 // buffers dead; alias buf0
    float* cs_sh = (float*)lds[0];
    if (tid < 128) cs_sh[tid] = 0.f;
    __syncthreads();
#pragma unroll
    for (int tj = 0; tj < 4; ++tj) {
        float v = csum[tj];
        v += __shfl_xor(v, 16); v += __shfl_xor(v, 32);
        if (quad == 0) atomicAdd(&cs_sh[wc0 + tj * 16 + l15], v);
    }
    __syncthreads();
    // fused: scale this block's disjoint 128x128 V patch in place
    int b = bh >> 4, h = bh & 15;
#pragma unroll
    for (int r = 0; r < 8; ++r) {
        int s = r * 256 + tid;
        int row = s >> 4, jc = s & 15;
        size_t off = ((size_t)(b * 2048 + kt * 128 + row)) * 2048 + h * 128 + jc * 8;
        float csv = cs_sh[row];
        bf16x8v vv = *reinterpret_cast<const bf16x8v*>(Vb + off);
        bf16x8v ov;
#pragma unroll
        for (int i = 0; i < 8; ++i) ov[i] = (__bf16)((float)vv[i] * csv);
        *reinterpret_cast<bf16x8v*>(Vb + off) = ov;
    }
}

// ---------------------------------------------------------------- launch
extern "C" void kernel_launch(void* const* d_in, const int* in_sizes, int n_in,
                              void* d_out, int out_size, void* d_ws, size_t ws_size,
                              hipStream_t stream) {
    (void)in_sizes; (void)n_in; (void)out_size; (void)ws_size;
    const float* x     = (const float*)d_in[0];
    const float* w_qkv = (const float*)d_in[1];
    const float* w_o   = (const float*)d_in[2];
    float* out = (float*)d_out;

    char* w = (char*)d_ws;
    auto alloc = [&](size_t bytes) {
        char* p = w; w += (bytes + 255) & ~(size_t)255; return p;
    };
    bf16_t* Xb    = (bf16_t*)alloc(4096ull * 2048 * 2);   // 16 MiB
    bf16_t* WqkvT = (bf16_t*)alloc(6144ull * 2048 * 2);   // 24 MiB
    bf16_t* WoT   = (bf16_t*)alloc(2048ull * 2048 * 2);   //  8 MiB
    bf16_t* Qb    = (bf16_t*)alloc(32ull * 2048 * 128 * 2); // 16 MiB [bh][s][d]
    bf16_t* Kb    = (bf16_t*)alloc(32ull * 2048 * 128 * 2);
    bf16_t* Vb    = (bf16_t*)alloc(4096ull * 2048 * 2);   // token-major
    float*  rlb   = (float*)alloc(32ull * 2048 * 4);      // 1/l per (bh, q)

    conv_x_k <<<8192, 256, 0, stream>>>(x, Xb);
    conv_wT_k<<<dim3(192, 64), 256, 0, stream>>>(w_qkv, WqkvT, 2048, 6144);
    conv_wT_k<<<dim3(64, 64),  256, 0, stream>>>(w_o,   WoT,   2048, 2048);

    gemm_bt_k<0, 6144, 2048><<<dim3(48, 32), 256, 0, stream>>>(
        Xb, WqkvT, nullptr, Qb, Kb, Vb);

    attn_l_k <<<dim3(16, 32), 256, 0, stream>>>(Qb, Kb, rlb);
    attn_cs_k<<<dim3(16, 32), 256, 0, stream>>>(Qb, Kb, rlb, Vb);

    gemm_bt_k<1, 2048, 2048><<<dim3(16, 32), 256, 0, stream>>>(
        Vb, WoT, out, nullptr, nullptr, nullptr);
}

// Round 3
// 415.620 us; speedup vs baseline: 1.0848x; 1.0848x over previous
//
#include <hip/hip_runtime.h>
#include <stdint.h>

// MegatronAttention: B=2, S=2048, H=2048, NH=16, DH=128.
// KEY INSIGHT: reference einsum 'bhqk,bhkd->bhkd' sums over q ->
//   values[b,h,k,d] = colsum_q(probs)[b,h,k] * v[b,h,k,d].
// Pipeline: convert->bf16, QKV GEMM (scatter epilogue, Q pre-scaled by
// 1/sqrt(d)*log2e), l-pass (row sums of exp2), cs-pass (weighted col sums),
// V scale, output GEMM.
// R3: native v_exp_f32 (__builtin_amdgcn_exp2f; plain exp2f lowered to the
// slow precise OCML path -> R2 regression), attn occupancy restructure:
// 64-row streamed tiles (32 KiB LDS/block), resident operand in registers,
// sweep split x2 across blocks with global-atomic partial sums.

typedef __bf16 bf16_t;
typedef __bf16 bf16x8v __attribute__((ext_vector_type(8)));
typedef __bf16 bf16x4v __attribute__((ext_vector_type(4)));
typedef float  f32x4v  __attribute__((ext_vector_type(4)));

#define DEVINL __device__ __forceinline__

// async global->LDS DMA, 16B per lane. LDS dest is wave-uniform base;
// HW writes lane i's data at base + i*16.
DEVINL void gll16(const bf16_t* g, void* lds_wave_uniform_base) {
    __builtin_amdgcn_global_load_lds(
        (__attribute__((address_space(1))) void*)g,
        (__attribute__((address_space(3))) void*)lds_wave_uniform_base,
        16, 0, 0);
}

// ---------------------------------------------------------------- converts
__global__ void conv_x_k(const float* __restrict__ in, bf16_t* __restrict__ out) {
    size_t i = ((size_t)blockIdx.x * 256 + threadIdx.x) * 4;
    float4 v = *reinterpret_cast<const float4*>(in + i);
    bf16x4v o;
    o[0] = (__bf16)v.x; o[1] = (__bf16)v.y; o[2] = (__bf16)v.z; o[3] = (__bf16)v.w;
    *reinterpret_cast<bf16x4v*>(out + i) = o;
}

// out[n][k] = (bf16) in[k][n]   (in: K x N fp32, out: N x K bf16)
// tile 64(k) x 32(n); bf16x8 vector stores.
__global__ void conv_wT_k(const float* __restrict__ in, bf16_t* __restrict__ out,
                          int K, int N) {
    __shared__ float t[64][33];
    int n0 = blockIdx.x * 32, k0 = blockIdx.y * 64;
    int tn = threadIdx.x & 31, tk = threadIdx.x >> 5;   // tk in 0..7
#pragma unroll
    for (int i = 0; i < 64; i += 8)
        t[tk + i][tn] = in[(size_t)(k0 + tk + i) * N + n0 + tn];
    __syncthreads();
    int n = threadIdx.x >> 3, kg = threadIdx.x & 7;
    bf16x8v o;
#pragma unroll
    for (int i = 0; i < 8; ++i) o[i] = (__bf16)t[kg * 8 + i][n];
    *reinterpret_cast<bf16x8v*>(out + (size_t)(n0 + n) * K + k0 + kg * 8) = o;
}

// ---------------------------------------------------------------- GEMM
// C[M,N] = A[M,K] @ B[N,K]^T, bf16 in, fp32 acc. 128x128 tile, BK=32,
// 256 threads (4 waves, 2x2 of 64x64), 16x16x32 MFMA.
// MODE 0: scatter-write QKV (Q/K head-contig [bh][s][d], V token-major),
//         Q pre-scaled by 1/sqrt(128)*log2(e) for exp2-based softmax.
// MODE 1: plain fp32 store to out[m*N+n].
template<int MODE, int N, int K>
__launch_bounds__(256, 2)
__global__ void gemm_bt_k(const bf16_t* __restrict__ A, const bf16_t* __restrict__ Bm,
                          float* __restrict__ outF,
                          bf16_t* __restrict__ Qb, bf16_t* __restrict__ Kb,
                          bf16_t* __restrict__ Vb)
{
    __shared__ __align__(16) bf16_t sA[512 * 8];   // 8 KiB
    __shared__ __align__(16) bf16_t sB[512 * 8];
    const int tid  = threadIdx.x;
    const int lane = tid & 63, wave = tid >> 6;
    const int quad = lane >> 4, l15 = lane & 15;
    const int rowBase = blockIdx.y * 128, colBase = blockIdx.x * 128;
    const int wr0 = (wave >> 1) * 64, wc0 = (wave & 1) * 64;

    const bf16_t* gA[2]; const bf16_t* gB[2]; uint32_t loff[2];
#pragma unroll
    for (int r = 0; r < 2; ++r) {
        int s = r * 256 + wave * 64 + lane;
        int row = s >> 2, j = s & 3;
        int cc = j ^ ((row >> 1) & 3);
        gA[r] = A  + (size_t)(rowBase + row) * K + cc * 8;
        gB[r] = Bm + (size_t)(colBase + row) * K + cc * 8;
        loff[r] = (uint32_t)(r * 256 + wave * 64) * 16;
    }
    int aoff[4], boff[4];
#pragma unroll
    for (int t = 0; t < 4; ++t) {
        int m = wr0 + t * 16 + l15;
        aoff[t] = (m * 4 + (quad ^ ((m >> 1) & 3))) * 8;
        int n = wc0 + t * 16 + l15;
        boff[t] = (n * 4 + (quad ^ ((n >> 1) & 3))) * 8;
    }

    f32x4v acc[4][4] = {};
    for (int kt = 0; kt < K / 32; ++kt) {
        __syncthreads();
#pragma unroll
        for (int r = 0; r < 2; ++r) {
            gll16(gA[r] + kt * 32, (char*)sA + loff[r]);
            gll16(gB[r] + kt * 32, (char*)sB + loff[r]);
        }
        __syncthreads();
        bf16x8v av[4], bv[4];
#pragma unroll
        for (int t = 0; t < 4; ++t) av[t] = *reinterpret_cast<const bf16x8v*>(sA + aoff[t]);
#pragma unroll
        for (int t = 0; t < 4; ++t) bv[t] = *reinterpret_cast<const bf16x8v*>(sB + boff[t]);
#pragma unroll
        for (int ti = 0; ti < 4; ++ti)
#pragma unroll
            for (int tj = 0; tj < 4; ++tj)
                acc[ti][tj] = __builtin_amdgcn_mfma_f32_16x16x32_bf16(
                                  av[ti], bv[tj], acc[ti][tj], 0, 0, 0);
    }

    constexpr float QS = 0.08838834764831845f * 1.44269504088896341f;
#pragma unroll
    for (int ti = 0; ti < 4; ++ti)
#pragma unroll
        for (int tj = 0; tj < 4; ++tj)
#pragma unroll
            for (int r = 0; r < 4; ++r) {
                int m = rowBase + wr0 + ti * 16 + quad * 4 + r;   // C row
                int n = colBase + wc0 + tj * 16 + l15;            // C col
                float v = acc[ti][tj][r];
                if constexpr (MODE == 0) {
                    int b = m >> 11, s = m & 2047;
                    int which = n >> 11, hd = n & 2047;           // uniform per block
                    if (which == 2) {
                        Vb[(size_t)m * 2048 + hd] = (__bf16)v;    // token-major
                    } else {
                        if (which == 0) v *= QS;                  // fold softmax scale
                        size_t idx = ((size_t)((b << 4) + (hd >> 7)) * 2048 + s) * 128
                                     + (hd & 127);
                        if (which == 0) Qb[idx] = (__bf16)v; else Kb[idx] = (__bf16)v;
                    }
                } else {
                    outF[(size_t)m * N + n] = v;
                }
            }
}

// ---------------------------------------------------------------- attention
// Resident 128-row operand lives in registers (staged once via LDS, hoisted).
// Streamed side: 64-row (16 KiB) double-buffered tiles -> 32 KiB LDS/block.
// Sweep split x2 across blocks; partials via global fp32 atomicAdd into
// zeroed l[bh][2048] / cs[bh][2048].
// Swizzle: 16B chunks, content chunk cc = j ^ (row&7) -> 2-way LDS (free).

__launch_bounds__(256, 2)
__global__ void attn_l_k(const bf16_t* __restrict__ Qb, const bf16_t* __restrict__ Kb,
                         float* __restrict__ lsums)
{
    __shared__ __align__(16) bf16_t lds[2][64 * 128];   // 2 x 16 KiB
    const int tid  = threadIdx.x;
    const int lane = tid & 63, wave = tid >> 6;
    const int quad = lane >> 4, l15 = lane & 15;
    const int qt = blockIdx.x, ks = blockIdx.y, bh = blockIdx.z;
    const bf16_t* Qg = Qb + (size_t)bh * 2048 * 128 + (size_t)qt * 128 * 128;
    const bf16_t* Kg = Kb + (size_t)bh * 2048 * 128 + (size_t)ks * 1024 * 128;
    const int wr0 = (wave >> 1) * 64;   // q rows (ti)
    const int wc0 = (wave & 1) * 32;    // k cols within 64-row tile (tj)

    int srow[4], scc[4]; uint32_t soff[4];
#pragma unroll
    for (int r = 0; r < 4; ++r) {
        int s = r * 256 + wave * 64 + lane;
        srow[r] = s >> 4; int j = s & 15;
        scc[r] = j ^ (srow[r] & 7);
        soff[r] = (uint32_t)(r * 256 + wave * 64) * 16;
    }
    // stage resident Q (128 rows) into lds[0..1] (contiguous 32 KiB)
#pragma unroll
    for (int r = 0; r < 4; ++r) {
        gll16(Qg + (size_t)srow[r] * 128 + scc[r] * 8, (char*)lds[0] + soff[r]);
        gll16(Qg + (size_t)(64 + srow[r]) * 128 + scc[r] * 8, (char*)lds[1] + soff[r]);
    }
    __syncthreads();
    bf16x8v qf[4][4];   // [kb][ti]
#pragma unroll
    for (int kb = 0; kb < 4; ++kb)
#pragma unroll
        for (int t = 0; t < 4; ++t) {
            int m = wr0 + t * 16 + l15;   // 0..127
            qf[kb][t] = *reinterpret_cast<const bf16x8v*>(
                &lds[0][0] + (m * 16 + ((kb * 4 + quad) ^ (m & 7))) * 8);
        }
    __syncthreads();    // Q reads drained before K overwrites
#pragma unroll
    for (int r = 0; r < 4; ++r)   // prefetch K tile 0
        gll16(Kg + (size_t)srow[r] * 128 + scc[r] * 8, (char*)lds[0] + soff[r]);

    float lsum[4][4] = {};
    for (int it = 0; it < 16; ++it) {
        __syncthreads();   // K[it] staged; prior buf reads done
        const bf16_t* cb = lds[it & 1];
        if (it < 15) {
            char* tgt = (char*)lds[(it & 1) ^ 1];
#pragma unroll
            for (int r = 0; r < 4; ++r)
                gll16(Kg + (size_t)((it + 1) * 64 + srow[r]) * 128 + scc[r] * 8,
                      tgt + soff[r]);
        }
        f32x4v sc[4][2] = {};
#pragma unroll
        for (int kb = 0; kb < 4; ++kb) {
            int ccq = kb * 4 + quad;
            bf16x8v bv[2];
#pragma unroll
            for (int tj = 0; tj < 2; ++tj) {
                int n = wc0 + tj * 16 + l15;   // 0..63
                bv[tj] = *reinterpret_cast<const bf16x8v*>(
                    cb + (n * 16 + (ccq ^ (n & 7))) * 8);
            }
#pragma unroll
            for (int ti = 0; ti < 4; ++ti)
#pragma unroll
                for (int tj = 0; tj < 2; ++tj)
                    sc[ti][tj] = __builtin_amdgcn_mfma_f32_16x16x32_bf16(
                                     qf[kb][ti], bv[tj], sc[ti][tj], 0, 0, 0);
        }
#pragma unroll
        for (int ti = 0; ti < 4; ++ti)
#pragma unroll
            for (int r = 0; r < 4; ++r)
                lsum[ti][r] += __builtin_amdgcn_exp2f(sc[ti][0][r])
                             + __builtin_amdgcn_exp2f(sc[ti][1][r]);
    }
    float* lg = lsums + (size_t)bh * 2048 + qt * 128;
#pragma unroll
    for (int ti = 0; ti < 4; ++ti)
#pragma unroll
        for (int r = 0; r < 4; ++r) {
            float v = lsum[ti][r];
            v += __shfl_xor(v, 1); v += __shfl_xor(v, 2);
            v += __shfl_xor(v, 4); v += __shfl_xor(v, 8);
            if (l15 == 0) atomicAdd(&lg[wr0 + ti * 16 + quad * 4 + r], v);
        }
}

__launch_bounds__(256, 2)
__global__ void attn_cs_k(const bf16_t* __restrict__ Qb, const bf16_t* __restrict__ Kb,
                          const float* __restrict__ lsums, float* __restrict__ cs)
{
    __shared__ __align__(16) bf16_t lds[2][64 * 128];   // 2 x 16 KiB
    const int tid  = threadIdx.x;
    const int lane = tid & 63, wave = tid >> 6;
    const int quad = lane >> 4, l15 = lane & 15;
    const int kt = blockIdx.x, qs = blockIdx.y, bh = blockIdx.z;
    const bf16_t* Kg = Kb + (size_t)bh * 2048 * 128 + (size_t)kt * 128 * 128;
    const bf16_t* Qg = Qb + (size_t)bh * 2048 * 128 + (size_t)qs * 1024 * 128;
    const float* lg = lsums + (size_t)bh * 2048 + (size_t)qs * 1024;
    const int wcK = (wave >> 1) * 64;   // resident k cols (tk)
    const int wq  = (wave & 1) * 32;    // streamed q rows per wave (ta)

    int srow[4], scc[4]; uint32_t soff[4];
#pragma unroll
    for (int r = 0; r < 4; ++r) {
        int s = r * 256 + wave * 64 + lane;
        srow[r] = s >> 4; int j = s & 15;
        scc[r] = j ^ (srow[r] & 7);
        soff[r] = (uint32_t)(r * 256 + wave * 64) * 16;
    }
    // stage resident K (128 rows) into lds[0..1]
#pragma unroll
    for (int r = 0; r < 4; ++r) {
        gll16(Kg + (size_t)srow[r] * 128 + scc[r] * 8, (char*)lds[0] + soff[r]);
        gll16(Kg + (size_t)(64 + srow[r]) * 128 + scc[r] * 8, (char*)lds[1] + soff[r]);
    }
    __syncthreads();
    bf16x8v kf[4][4];   // [kb][tk]
#pragma unroll
    for (int kb = 0; kb < 4; ++kb)
#pragma unroll
        for (int t = 0; t < 4; ++t) {
            int n = wcK + t * 16 + l15;   // 0..127
            kf[kb][t] = *reinterpret_cast<const bf16x8v*>(
                &lds[0][0] + (n * 16 + ((kb * 4 + quad) ^ (n & 7))) * 8);
        }
    __syncthreads();
#pragma unroll
    for (int r = 0; r < 4; ++r)   // prefetch Q tile 0
        gll16(Qg + (size_t)srow[r] * 128 + scc[r] * 8, (char*)lds[0] + soff[r]);

    float csum[4] = {};
    for (int it = 0; it < 16; ++it) {
        __syncthreads();
        const bf16_t* cb = lds[it & 1];
        if (it < 15) {
            char* tgt = (char*)lds[(it & 1) ^ 1];
#pragma unroll
            for (int r = 0; r < 4; ++r)
                gll16(Qg + (size_t)((it + 1) * 64 + srow[r]) * 128 + scc[r] * 8,
                      tgt + soff[r]);
        }
        f32x4v sc[2][4] = {};
#pragma unroll
        for (int kb = 0; kb < 4; ++kb) {
            int ccq = kb * 4 + quad;
            bf16x8v av[2];
#pragma unroll
            for (int ta = 0; ta < 2; ++ta) {
                int m = wq + ta * 16 + l15;   // 0..63
                av[ta] = *reinterpret_cast<const bf16x8v*>(
                    cb + (m * 16 + (ccq ^ (m & 7))) * 8);
            }
#pragma unroll
            for (int ta = 0; ta < 2; ++ta)
#pragma unroll
                for (int tk = 0; tk < 4; ++tk)
                    sc[ta][tk] = __builtin_amdgcn_mfma_f32_16x16x32_bf16(
                                     av[ta], kf[kb][tk], sc[ta][tk], 0, 0, 0);
        }
#pragma unroll
        for (int ta = 0; ta < 2; ++ta) {
            f32x4v lv = *reinterpret_cast<const f32x4v*>(
                lg + it * 64 + wq + ta * 16 + quad * 4);
#pragma unroll
            for (int r = 0; r < 4; ++r) {
                float rli = __builtin_amdgcn_rcpf(lv[r]);
#pragma unroll
                for (int tk = 0; tk < 4; ++tk)
                    csum[tk] += __builtin_amdgcn_exp2f(sc[ta][tk][r]) * rli;
            }
        }
    }
    float* cg = cs + (size_t)bh * 2048 + kt * 128;
#pragma unroll
    for (int tk = 0; tk < 4; ++tk) {
        float v = csum[tk];
        v += __shfl_xor(v, 16); v += __shfl_xor(v, 32);
        if (quad == 0) atomicAdd(&cg[wcK + tk * 16 + l15], v);
    }
}

// Vb[b*2048+s][h*128+d] *= cs[(b*16+h)][s]
__global__ void vscale_k(bf16_t* __restrict__ Vb, const float* __restrict__ cs) {
    int row = blockIdx.x;              // b*2048 + s
    int tid = threadIdx.x;
    int b = row >> 11, s = row & 2047, h = tid >> 4;
    float c = cs[((size_t)((b << 4) + h)) * 2048 + s];
    size_t off = (size_t)row * 2048 + tid * 8;
    bf16x8v v = *reinterpret_cast<const bf16x8v*>(Vb + off);
    bf16x8v o;
#pragma unroll
    for (int i = 0; i < 8; ++i) o[i] = (__bf16)((float)v[i] * c);
    *reinterpret_cast<bf16x8v*>(Vb + off) = o;
}

// ---------------------------------------------------------------- launch
extern "C" void kernel_launch(void* const* d_in, const int* in_sizes, int n_in,
                              void* d_out, int out_size, void* d_ws, size_t ws_size,
                              hipStream_t stream) {
    (void)in_sizes; (void)n_in; (void)out_size; (void)ws_size;
    const float* x     = (const float*)d_in[0];
    const float* w_qkv = (const float*)d_in[1];
    const float* w_o   = (const float*)d_in[2];
    float* out = (float*)d_out;

    char* w = (char*)d_ws;
    auto alloc = [&](size_t bytes) {
        char* p = w; w += (bytes + 255) & ~(size_t)255; return p;
    };
    bf16_t* Xb    = (bf16_t*)alloc(4096ull * 2048 * 2);   // 16 MiB
    bf16_t* WqkvT = (bf16_t*)alloc(6144ull * 2048 * 2);   // 24 MiB
    bf16_t* WoT   = (bf16_t*)alloc(2048ull * 2048 * 2);   //  8 MiB
    bf16_t* Qb    = (bf16_t*)alloc(32ull * 2048 * 128 * 2); // 16 MiB [bh][s][d]
    bf16_t* Kb    = (bf16_t*)alloc(32ull * 2048 * 128 * 2);
    bf16_t* Vb    = (bf16_t*)alloc(4096ull * 2048 * 2);   // token-major
    float*  lbuf  = (float*)alloc(32ull * 2048 * 4);      // l row sums (atomic)
    float*  csbuf = (float*)alloc(32ull * 2048 * 4);      // col sums (atomic)

    hipMemsetAsync(lbuf, 0, 2ull * 32 * 2048 * 4, stream);   // lbuf+csbuf adjacent

    conv_x_k <<<8192, 256, 0, stream>>>(x, Xb);
    conv_wT_k<<<dim3(192, 32), 256, 0, stream>>>(w_qkv, WqkvT, 2048, 6144);
    conv_wT_k<<<dim3(64, 32),  256, 0, stream>>>(w_o,   WoT,   2048, 2048);

    gemm_bt_k<0, 6144, 2048><<<dim3(48, 32), 256, 0, stream>>>(
        Xb, WqkvT, nullptr, Qb, Kb, Vb);

    attn_l_k <<<dim3(16, 2, 32), 256, 0, stream>>>(Qb, Kb, lbuf);
    attn_cs_k<<<dim3(16, 2, 32), 256, 0, stream>>>(Qb, Kb, lbuf, csbuf);
    vscale_k <<<4096, 256, 0, stream>>>(Vb, csbuf);

    gemm_bt_k<1, 2048, 2048><<<dim3(16, 32), 256, 0, stream>>>(
        Vb, WoT, out, nullptr, nullptr, nullptr);
}

// Round 4
// 405.751 us; speedup vs baseline: 1.1112x; 1.0243x over previous
//
#include <hip/hip_runtime.h>
#include <stdint.h>

// MegatronAttention: B=2, S=2048, H=2048, NH=16, DH=128.
// KEY INSIGHT: reference einsum 'bhqk,bhkd->bhkd' sums over q ->
//   values[b,h,k,d] = colsum_q(probs)[b,h,k] * v[b,h,k,d].
// Pipeline: convert->bf16, QKV GEMM (scatter epilogue, Q pre-scaled by
// 1/sqrt(d)*log2e), l-pass (row sums of exp2), recip, cs-pass (weighted col
// sums), V scale, output GEMM.
// R4: attn occupancy 2->4 blocks/CU (the barrier vmcnt-drain stall at
// 2 blocks/CU was ~50% of attn time): resident frags ti=4 -> ti=2 per wave
// (32 VGPR), __launch_bounds__(256,4), both passes split x2 -> grid 1024
// = exactly 4 blocks/CU. recip hoisted out of the cs inner loop.

typedef __bf16 bf16_t;
typedef __bf16 bf16x8v __attribute__((ext_vector_type(8)));
typedef __bf16 bf16x4v __attribute__((ext_vector_type(4)));
typedef float  f32x4v  __attribute__((ext_vector_type(4)));

#define DEVINL __device__ __forceinline__

// async global->LDS DMA, 16B per lane. LDS dest is wave-uniform base;
// HW writes lane i's data at base + i*16.
DEVINL void gll16(const bf16_t* g, void* lds_wave_uniform_base) {
    __builtin_amdgcn_global_load_lds(
        (__attribute__((address_space(1))) void*)g,
        (__attribute__((address_space(3))) void*)lds_wave_uniform_base,
        16, 0, 0);
}

// ---------------------------------------------------------------- converts
__global__ void conv_x_k(const float* __restrict__ in, bf16_t* __restrict__ out) {
    size_t i = ((size_t)blockIdx.x * 256 + threadIdx.x) * 4;
    float4 v = *reinterpret_cast<const float4*>(in + i);
    bf16x4v o;
    o[0] = (__bf16)v.x; o[1] = (__bf16)v.y; o[2] = (__bf16)v.z; o[3] = (__bf16)v.w;
    *reinterpret_cast<bf16x4v*>(out + i) = o;
}

// out[n][k] = (bf16) in[k][n]   (in: K x N fp32, out: N x K bf16)
__global__ void conv_wT_k(const float* __restrict__ in, bf16_t* __restrict__ out,
                          int K, int N) {
    __shared__ float t[64][33];
    int n0 = blockIdx.x * 32, k0 = blockIdx.y * 64;
    int tn = threadIdx.x & 31, tk = threadIdx.x >> 5;   // tk in 0..7
#pragma unroll
    for (int i = 0; i < 64; i += 8)
        t[tk + i][tn] = in[(size_t)(k0 + tk + i) * N + n0 + tn];
    __syncthreads();
    int n = threadIdx.x >> 3, kg = threadIdx.x & 7;
    bf16x8v o;
#pragma unroll
    for (int i = 0; i < 8; ++i) o[i] = (__bf16)t[kg * 8 + i][n];
    *reinterpret_cast<bf16x8v*>(out + (size_t)(n0 + n) * K + k0 + kg * 8) = o;
}

// ---------------------------------------------------------------- GEMM
// C[M,N] = A[M,K] @ B[N,K]^T, bf16 in, fp32 acc. 128x128 tile, BK=32,
// 256 threads (4 waves, 2x2 of 64x64), 16x16x32 MFMA.
// MODE 0: scatter-write QKV (Q/K head-contig [bh][s][d], V token-major),
//         Q pre-scaled by 1/sqrt(128)*log2(e) for exp2-based softmax.
// MODE 1: plain fp32 store to out[m*N+n].
template<int MODE, int N, int K>
__launch_bounds__(256, 2)
__global__ void gemm_bt_k(const bf16_t* __restrict__ A, const bf16_t* __restrict__ Bm,
                          float* __restrict__ outF,
                          bf16_t* __restrict__ Qb, bf16_t* __restrict__ Kb,
                          bf16_t* __restrict__ Vb)
{
    __shared__ __align__(16) bf16_t sA[512 * 8];   // 8 KiB
    __shared__ __align__(16) bf16_t sB[512 * 8];
    const int tid  = threadIdx.x;
    const int lane = tid & 63, wave = tid >> 6;
    const int quad = lane >> 4, l15 = lane & 15;
    const int rowBase = blockIdx.y * 128, colBase = blockIdx.x * 128;
    const int wr0 = (wave >> 1) * 64, wc0 = (wave & 1) * 64;

    const bf16_t* gA[2]; const bf16_t* gB[2]; uint32_t loff[2];
#pragma unroll
    for (int r = 0; r < 2; ++r) {
        int s = r * 256 + wave * 64 + lane;
        int row = s >> 2, j = s & 3;
        int cc = j ^ ((row >> 1) & 3);
        gA[r] = A  + (size_t)(rowBase + row) * K + cc * 8;
        gB[r] = Bm + (size_t)(colBase + row) * K + cc * 8;
        loff[r] = (uint32_t)(r * 256 + wave * 64) * 16;
    }
    int aoff[4], boff[4];
#pragma unroll
    for (int t = 0; t < 4; ++t) {
        int m = wr0 + t * 16 + l15;
        aoff[t] = (m * 4 + (quad ^ ((m >> 1) & 3))) * 8;
        int n = wc0 + t * 16 + l15;
        boff[t] = (n * 4 + (quad ^ ((n >> 1) & 3))) * 8;
    }

    f32x4v acc[4][4] = {};
    for (int kt = 0; kt < K / 32; ++kt) {
        __syncthreads();
#pragma unroll
        for (int r = 0; r < 2; ++r) {
            gll16(gA[r] + kt * 32, (char*)sA + loff[r]);
            gll16(gB[r] + kt * 32, (char*)sB + loff[r]);
        }
        __syncthreads();
        bf16x8v av[4], bv[4];
#pragma unroll
        for (int t = 0; t < 4; ++t) av[t] = *reinterpret_cast<const bf16x8v*>(sA + aoff[t]);
#pragma unroll
        for (int t = 0; t < 4; ++t) bv[t] = *reinterpret_cast<const bf16x8v*>(sB + boff[t]);
#pragma unroll
        for (int ti = 0; ti < 4; ++ti)
#pragma unroll
            for (int tj = 0; tj < 4; ++tj)
                acc[ti][tj] = __builtin_amdgcn_mfma_f32_16x16x32_bf16(
                                  av[ti], bv[tj], acc[ti][tj], 0, 0, 0);
    }

    constexpr float QS = 0.08838834764831845f * 1.44269504088896341f;
#pragma unroll
    for (int ti = 0; ti < 4; ++ti)
#pragma unroll
        for (int tj = 0; tj < 4; ++tj)
#pragma unroll
            for (int r = 0; r < 4; ++r) {
                int m = rowBase + wr0 + ti * 16 + quad * 4 + r;   // C row
                int n = colBase + wc0 + tj * 16 + l15;            // C col
                float v = acc[ti][tj][r];
                if constexpr (MODE == 0) {
                    int b = m >> 11, s = m & 2047;
                    int which = n >> 11, hd = n & 2047;           // uniform per block
                    if (which == 2) {
                        Vb[(size_t)m * 2048 + hd] = (__bf16)v;    // token-major
                    } else {
                        if (which == 0) v *= QS;                  // fold softmax scale
                        size_t idx = ((size_t)((b << 4) + (hd >> 7)) * 2048 + s) * 128
                                     + (hd & 127);
                        if (which == 0) Qb[idx] = (__bf16)v; else Kb[idx] = (__bf16)v;
                    }
                } else {
                    outF[(size_t)m * N + n] = v;
                }
            }
}

// ---------------------------------------------------------------- attention
// Resident 128-row operand: each wave hoists 32 rows (ti/tk=2, 32 VGPR) and
// sweeps all 4 column-tiles of the streamed 64-row (16 KiB) dbuf tile.
// 32 KiB LDS + <=128 VGPR -> 4 blocks/CU (barrier drains overlap across
// blocks). Sweeps split x2; partials via global fp32 atomicAdd.
// Swizzle: 16B chunks, content chunk cc at slot j: cc = j ^ (row&7).

__launch_bounds__(256, 4)
__global__ void attn_l_k(const bf16_t* __restrict__ Qb, const bf16_t* __restrict__ Kb,
                         float* __restrict__ lsums)
{
    __shared__ __align__(16) bf16_t lds[2][64 * 128];   // 2 x 16 KiB
    const int tid  = threadIdx.x;
    const int lane = tid & 63, wave = tid >> 6;
    const int quad = lane >> 4, l15 = lane & 15;
    const int qt = blockIdx.x, ks = blockIdx.y, bh = blockIdx.z;
    const bf16_t* Qg = Qb + (size_t)bh * 2048 * 128 + (size_t)qt * 128 * 128;
    const bf16_t* Kg = Kb + (size_t)bh * 2048 * 128 + (size_t)ks * 1024 * 128;

    int srow[4], scc[4]; uint32_t soff[4];
#pragma unroll
    for (int r = 0; r < 4; ++r) {
        int s = r * 256 + wave * 64 + lane;
        srow[r] = s >> 4; int j = s & 15;
        scc[r] = j ^ (srow[r] & 7);
        soff[r] = (uint32_t)(r * 256 + wave * 64) * 16;
    }
    // stage resident Q (128 rows, 32 KiB) into lds[0..1]
#pragma unroll
    for (int r = 0; r < 4; ++r) {
        gll16(Qg + (size_t)srow[r] * 128 + scc[r] * 8, (char*)lds[0] + soff[r]);
        gll16(Qg + (size_t)(64 + srow[r]) * 128 + scc[r] * 8, (char*)lds[1] + soff[r]);
    }
    __syncthreads();
    bf16x8v qf[4][2];   // [kb][ti]  wave owns q rows [wave*32, wave*32+32)
#pragma unroll
    for (int kb = 0; kb < 4; ++kb)
#pragma unroll
        for (int t = 0; t < 2; ++t) {
            int m = wave * 32 + t * 16 + l15;   // 0..127
            qf[kb][t] = *reinterpret_cast<const bf16x8v*>(
                &lds[0][0] + (m * 16 + ((kb * 4 + quad) ^ (m & 7))) * 8);
        }
    __syncthreads();    // Q reads drained before K overwrites
#pragma unroll
    for (int r = 0; r < 4; ++r)   // prefetch K tile 0
        gll16(Kg + (size_t)srow[r] * 128 + scc[r] * 8, (char*)lds[0] + soff[r]);

    float lsum[2][4] = {};
    for (int it = 0; it < 16; ++it) {
        __syncthreads();   // K[it] staged; prior buf reads done
        const bf16_t* cb = lds[it & 1];
        if (it < 15) {
            char* tgt = (char*)lds[(it & 1) ^ 1];
#pragma unroll
            for (int r = 0; r < 4; ++r)
                gll16(Kg + (size_t)((it + 1) * 64 + srow[r]) * 128 + scc[r] * 8,
                      tgt + soff[r]);
        }
        f32x4v sc[2][4] = {};
#pragma unroll
        for (int kb = 0; kb < 4; ++kb) {
            int ccq = kb * 4 + quad;
            bf16x8v bv[4];
#pragma unroll
            for (int tj = 0; tj < 4; ++tj) {
                int n = tj * 16 + l15;   // 0..63 (all waves sweep all cols)
                bv[tj] = *reinterpret_cast<const bf16x8v*>(
                    cb + (n * 16 + (ccq ^ (n & 7))) * 8);
            }
#pragma unroll
            for (int ti = 0; ti < 2; ++ti)
#pragma unroll
                for (int tj = 0; tj < 4; ++tj)
                    sc[ti][tj] = __builtin_amdgcn_mfma_f32_16x16x32_bf16(
                                     qf[kb][ti], bv[tj], sc[ti][tj], 0, 0, 0);
        }
#pragma unroll
        for (int ti = 0; ti < 2; ++ti)
#pragma unroll
            for (int r = 0; r < 4; ++r) {
                float e = 0.f;
#pragma unroll
                for (int tj = 0; tj < 4; ++tj) e += __builtin_amdgcn_exp2f(sc[ti][tj][r]);
                lsum[ti][r] += e;
            }
    }
    float* lg = lsums + (size_t)bh * 2048 + qt * 128;
#pragma unroll
    for (int ti = 0; ti < 2; ++ti)
#pragma unroll
        for (int r = 0; r < 4; ++r) {
            float v = lsum[ti][r];
            v += __shfl_xor(v, 1); v += __shfl_xor(v, 2);
            v += __shfl_xor(v, 4); v += __shfl_xor(v, 8);
            if (l15 == 0)
                atomicAdd(&lg[wave * 32 + ti * 16 + quad * 4 + r], v);
        }
}

// in-place: l -> 1/l  (65536 floats)
__global__ void recip_k(float* __restrict__ p) {
    size_t i = ((size_t)blockIdx.x * 256 + threadIdx.x) * 4;
    f32x4v v = *reinterpret_cast<const f32x4v*>(p + i);
#pragma unroll
    for (int j = 0; j < 4; ++j) v[j] = 1.0f / v[j];
    *reinterpret_cast<f32x4v*>(p + i) = v;
}

__launch_bounds__(256, 4)
__global__ void attn_cs_k(const bf16_t* __restrict__ Qb, const bf16_t* __restrict__ Kb,
                          const float* __restrict__ rls, float* __restrict__ cs)
{
    __shared__ __align__(16) bf16_t lds[2][64 * 128];   // 2 x 16 KiB
    const int tid  = threadIdx.x;
    const int lane = tid & 63, wave = tid >> 6;
    const int quad = lane >> 4, l15 = lane & 15;
    const int kt = blockIdx.x, qs = blockIdx.y, bh = blockIdx.z;
    const bf16_t* Kg = Kb + (size_t)bh * 2048 * 128 + (size_t)kt * 128 * 128;
    const bf16_t* Qg = Qb + (size_t)bh * 2048 * 128 + (size_t)qs * 1024 * 128;
    const float* rlg = rls + (size_t)bh * 2048 + (size_t)qs * 1024;

    int srow[4], scc[4]; uint32_t soff[4];
#pragma unroll
    for (int r = 0; r < 4; ++r) {
        int s = r * 256 + wave * 64 + lane;
        srow[r] = s >> 4; int j = s & 15;
        scc[r] = j ^ (srow[r] & 7);
        soff[r] = (uint32_t)(r * 256 + wave * 64) * 16;
    }
    // stage resident K (128 rows, 32 KiB) into lds[0..1]
#pragma unroll
    for (int r = 0; r < 4; ++r) {
        gll16(Kg + (size_t)srow[r] * 128 + scc[r] * 8, (char*)lds[0] + soff[r]);
        gll16(Kg + (size_t)(64 + srow[r]) * 128 + scc[r] * 8, (char*)lds[1] + soff[r]);
    }
    __syncthreads();
    bf16x8v kf[4][2];   // [kb][tk]  wave owns k cols [wave*32, wave*32+32)
#pragma unroll
    for (int kb = 0; kb < 4; ++kb)
#pragma unroll
        for (int t = 0; t < 2; ++t) {
            int n = wave * 32 + t * 16 + l15;   // 0..127
            kf[kb][t] = *reinterpret_cast<const bf16x8v*>(
                &lds[0][0] + (n * 16 + ((kb * 4 + quad) ^ (n & 7))) * 8);
        }
    __syncthreads();
#pragma unroll
    for (int r = 0; r < 4; ++r)   // prefetch Q tile 0
        gll16(Qg + (size_t)srow[r] * 128 + scc[r] * 8, (char*)lds[0] + soff[r]);

    float csum[2] = {};
    for (int it = 0; it < 16; ++it) {
        __syncthreads();
        const bf16_t* cb = lds[it & 1];
        if (it < 15) {
            char* tgt = (char*)lds[(it & 1) ^ 1];
#pragma unroll
            for (int r = 0; r < 4; ++r)
                gll16(Qg + (size_t)((it + 1) * 64 + srow[r]) * 128 + scc[r] * 8,
                      tgt + soff[r]);
        }
        f32x4v sc[4][2] = {};
#pragma unroll
        for (int kb = 0; kb < 4; ++kb) {
            int ccq = kb * 4 + quad;
            bf16x8v av[4];
#pragma unroll
            for (int ta = 0; ta < 4; ++ta) {
                int m = ta * 16 + l15;   // 0..63 streamed q rows
                av[ta] = *reinterpret_cast<const bf16x8v*>(
                    cb + (m * 16 + (ccq ^ (m & 7))) * 8);
            }
#pragma unroll
            for (int ta = 0; ta < 4; ++ta)
#pragma unroll
                for (int tk = 0; tk < 2; ++tk)
                    sc[ta][tk] = __builtin_amdgcn_mfma_f32_16x16x32_bf16(
                                     av[ta], kf[kb][tk], sc[ta][tk], 0, 0, 0);
        }
#pragma unroll
        for (int ta = 0; ta < 4; ++ta) {
            f32x4v rlv = *reinterpret_cast<const f32x4v*>(
                rlg + it * 64 + ta * 16 + quad * 4);
#pragma unroll
            for (int r = 0; r < 4; ++r)
#pragma unroll
                for (int tk = 0; tk < 2; ++tk)
                    csum[tk] += __builtin_amdgcn_exp2f(sc[ta][tk][r]) * rlv[r];
        }
    }
    float* cg = cs + (size_t)bh * 2048 + kt * 128;
#pragma unroll
    for (int tk = 0; tk < 2; ++tk) {
        float v = csum[tk];
        v += __shfl_xor(v, 16); v += __shfl_xor(v, 32);
        if (quad == 0)
            atomicAdd(&cg[wave * 32 + tk * 16 + l15], v);
    }
}

// Vb[b*2048+s][h*128+d] *= cs[(b*16+h)][s]
__global__ void vscale_k(bf16_t* __restrict__ Vb, const float* __restrict__ cs) {
    int row = blockIdx.x;              // b*2048 + s
    int tid = threadIdx.x;
    int b = row >> 11, s = row & 2047, h = tid >> 4;
    float c = cs[((size_t)((b << 4) + h)) * 2048 + s];
    size_t off = (size_t)row * 2048 + tid * 8;
    bf16x8v v = *reinterpret_cast<const bf16x8v*>(Vb + off);
    bf16x8v o;
#pragma unroll
    for (int i = 0; i < 8; ++i) o[i] = (__bf16)((float)v[i] * c);
    *reinterpret_cast<bf16x8v*>(Vb + off) = o;
}

// ---------------------------------------------------------------- launch
extern "C" void kernel_launch(void* const* d_in, const int* in_sizes, int n_in,
                              void* d_out, int out_size, void* d_ws, size_t ws_size,
                              hipStream_t stream) {
    (void)in_sizes; (void)n_in; (void)out_size; (void)ws_size;
    const float* x     = (const float*)d_in[0];
    const float* w_qkv = (const float*)d_in[1];
    const float* w_o   = (const float*)d_in[2];
    float* out = (float*)d_out;

    char* w = (char*)d_ws;
    auto alloc = [&](size_t bytes) {
        char* p = w; w += (bytes + 255) & ~(size_t)255; return p;
    };
    bf16_t* Xb    = (bf16_t*)alloc(4096ull * 2048 * 2);   // 16 MiB
    bf16_t* WqkvT = (bf16_t*)alloc(6144ull * 2048 * 2);   // 24 MiB
    bf16_t* WoT   = (bf16_t*)alloc(2048ull * 2048 * 2);   //  8 MiB
    bf16_t* Qb    = (bf16_t*)alloc(32ull * 2048 * 128 * 2); // 16 MiB [bh][s][d]
    bf16_t* Kb    = (bf16_t*)alloc(32ull * 2048 * 128 * 2);
    bf16_t* Vb    = (bf16_t*)alloc(4096ull * 2048 * 2);   // token-major
    float*  lbuf  = (float*)alloc(32ull * 2048 * 4);      // l sums -> 1/l
    float*  csbuf = (float*)alloc(32ull * 2048 * 4);      // col sums (atomic)

    hipMemsetAsync(lbuf, 0, 2ull * 32 * 2048 * 4, stream);   // lbuf+csbuf adjacent

    conv_x_k <<<8192, 256, 0, stream>>>(x, Xb);
    conv_wT_k<<<dim3(192, 32), 256, 0, stream>>>(w_qkv, WqkvT, 2048, 6144);
    conv_wT_k<<<dim3(64, 32),  256, 0, stream>>>(w_o,   WoT,   2048, 2048);

    gemm_bt_k<0, 6144, 2048><<<dim3(48, 32), 256, 0, stream>>>(
        Xb, WqkvT, nullptr, Qb, Kb, Vb);

    attn_l_k <<<dim3(16, 2, 32), 256, 0, stream>>>(Qb, Kb, lbuf);
    recip_k  <<<64, 256, 0, stream>>>(lbuf);
    attn_cs_k<<<dim3(16, 2, 32), 256, 0, stream>>>(Qb, Kb, lbuf, csbuf);
    vscale_k <<<4096, 256, 0, stream>>>(Vb, csbuf);

    gemm_bt_k<1, 2048, 2048><<<dim3(16, 32), 256, 0, stream>>>(
        Vb, WoT, out, nullptr, nullptr, nullptr);
}

// Round 5
// 372.521 us; speedup vs baseline: 1.2103x; 1.0892x over previous
//
#include <hip/hip_runtime.h>
#include <stdint.h>

// MegatronAttention: B=2, S=2048, H=2048, NH=16, DH=128.
// KEY INSIGHT: reference einsum 'bhqk,bhkd->bhkd' sums over q ->
//   values[b,h,k,d] = colsum_q(probs)[b,h,k] * v[b,h,k,d].
// Pipeline: convert->bf16, QKV GEMM (scatter epilogue, Q pre-scaled by
// 1/sqrt(d)*log2e), l-pass (writes 1/rowsum directly), cs-pass (weighted
// col sums + fused V scale), output GEMM.
// R5: (a) GEMM BK=32->64: half the barrier drains, launch_bounds(256,3)
// for 3 blocks/CU (m97 config). (b) attn passes unsplit (grid 512, 32-iter
// sweep, 8 ds_read : 32 MFMA wave config): kills memset/recip/vscale
// kernels + all global atomics, and makes attn visible in top-5 if slow.

typedef __bf16 bf16_t;
typedef __bf16 bf16x8v __attribute__((ext_vector_type(8)));
typedef __bf16 bf16x4v __attribute__((ext_vector_type(4)));
typedef float  f32x4v  __attribute__((ext_vector_type(4)));

#define DEVINL __device__ __forceinline__

// async global->LDS DMA, 16B per lane. LDS dest is wave-uniform base;
// HW writes lane i's data at base + i*16.
DEVINL void gll16(const bf16_t* g, void* lds_wave_uniform_base) {
    __builtin_amdgcn_global_load_lds(
        (__attribute__((address_space(1))) void*)g,
        (__attribute__((address_space(3))) void*)lds_wave_uniform_base,
        16, 0, 0);
}

// ---------------------------------------------------------------- converts
__global__ void conv_x_k(const float* __restrict__ in, bf16_t* __restrict__ out) {
    size_t i = ((size_t)blockIdx.x * 256 + threadIdx.x) * 4;
    float4 v = *reinterpret_cast<const float4*>(in + i);
    bf16x4v o;
    o[0] = (__bf16)v.x; o[1] = (__bf16)v.y; o[2] = (__bf16)v.z; o[3] = (__bf16)v.w;
    *reinterpret_cast<bf16x4v*>(out + i) = o;
}

// out[n][k] = (bf16) in[k][n]   (in: K x N fp32, out: N x K bf16)
__global__ void conv_wT_k(const float* __restrict__ in, bf16_t* __restrict__ out,
                          int K, int N) {
    __shared__ float t[64][33];
    int n0 = blockIdx.x * 32, k0 = blockIdx.y * 64;
    int tn = threadIdx.x & 31, tk = threadIdx.x >> 5;   // tk in 0..7
#pragma unroll
    for (int i = 0; i < 64; i += 8)
        t[tk + i][tn] = in[(size_t)(k0 + tk + i) * N + n0 + tn];
    __syncthreads();
    int n = threadIdx.x >> 3, kg = threadIdx.x & 7;
    bf16x8v o;
#pragma unroll
    for (int i = 0; i < 8; ++i) o[i] = (__bf16)t[kg * 8 + i][n];
    *reinterpret_cast<bf16x8v*>(out + (size_t)(n0 + n) * K + k0 + kg * 8) = o;
}

// ---------------------------------------------------------------- GEMM
// C[M,N] = A[M,K] @ B[N,K]^T, bf16 in, fp32 acc. 128x128 tile, BK=64,
// 256 threads (4 waves, 2x2 of 64x64), 16x16x32 MFMA, 32 K-iters.
// LDS: sA/sB 128 rows x 64 k x bf16 = 16 KiB each. Row = 8 chunks of 16B,
// slot j holds content chunk cc = j ^ (row&7)  -> frag ds_read_b128 lands
// 2-way on banks (free), staging row stays one 128B segment.
// MODE 0: scatter-write QKV (Q/K head-contig [bh][s][d], V token-major),
//         Q pre-scaled by 1/sqrt(128)*log2(e). MODE 1: fp32 store.
template<int MODE, int N, int K>
__launch_bounds__(256, 3)
__global__ void gemm_bt_k(const bf16_t* __restrict__ A, const bf16_t* __restrict__ Bm,
                          float* __restrict__ outF,
                          bf16_t* __restrict__ Qb, bf16_t* __restrict__ Kb,
                          bf16_t* __restrict__ Vb)
{
    __shared__ __align__(16) bf16_t sA[128 * 64];   // 16 KiB
    __shared__ __align__(16) bf16_t sB[128 * 64];
    const int tid  = threadIdx.x;
    const int lane = tid & 63, wave = tid >> 6;
    const int quad = lane >> 4, l15 = lane & 15;
    const int rowBase = blockIdx.y * 128, colBase = blockIdx.x * 128;
    const int wr0 = (wave >> 1) * 64, wc0 = (wave & 1) * 64;

    // staging: 4 slots of 256 per matrix; slot s: row=s>>3, j=s&7, cc=j^(row&7)
    const bf16_t* gA[4]; const bf16_t* gB[4]; uint32_t loff[4];
#pragma unroll
    for (int r = 0; r < 4; ++r) {
        int s = r * 256 + wave * 64 + lane;
        int row = s >> 3, j = s & 7;
        int cc = j ^ (row & 7);
        gA[r] = A  + (size_t)(rowBase + row) * K + cc * 8;
        gB[r] = Bm + (size_t)(colBase + row) * K + cc * 8;
        loff[r] = (uint32_t)(r * 256 + wave * 64) * 16;
    }
    int aoff[2][4], boff[2][4];   // [kstep][t] LDS elem offsets
#pragma unroll
    for (int ks = 0; ks < 2; ++ks)
#pragma unroll
        for (int t = 0; t < 4; ++t) {
            int m = wr0 + t * 16 + l15;
            aoff[ks][t] = (m * 8 + ((ks * 4 + quad) ^ (m & 7))) * 8;
            int n = wc0 + t * 16 + l15;
            boff[ks][t] = (n * 8 + ((ks * 4 + quad) ^ (n & 7))) * 8;
        }

    f32x4v acc[4][4] = {};
    for (int kt = 0; kt < K / 64; ++kt) {
        __syncthreads();
#pragma unroll
        for (int r = 0; r < 4; ++r) {
            gll16(gA[r] + kt * 64, (char*)sA + loff[r]);
            gll16(gB[r] + kt * 64, (char*)sB + loff[r]);
        }
        __syncthreads();
#pragma unroll
        for (int ks = 0; ks < 2; ++ks) {
            bf16x8v av[4], bv[4];
#pragma unroll
            for (int t = 0; t < 4; ++t) av[t] = *reinterpret_cast<const bf16x8v*>(sA + aoff[ks][t]);
#pragma unroll
            for (int t = 0; t < 4; ++t) bv[t] = *reinterpret_cast<const bf16x8v*>(sB + boff[ks][t]);
#pragma unroll
            for (int ti = 0; ti < 4; ++ti)
#pragma unroll
                for (int tj = 0; tj < 4; ++tj)
                    acc[ti][tj] = __builtin_amdgcn_mfma_f32_16x16x32_bf16(
                                      av[ti], bv[tj], acc[ti][tj], 0, 0, 0);
        }
    }

    constexpr float QS = 0.08838834764831845f * 1.44269504088896341f;
#pragma unroll
    for (int ti = 0; ti < 4; ++ti)
#pragma unroll
        for (int tj = 0; tj < 4; ++tj)
#pragma unroll
            for (int r = 0; r < 4; ++r) {
                int m = rowBase + wr0 + ti * 16 + quad * 4 + r;   // C row
                int n = colBase + wc0 + tj * 16 + l15;            // C col
                float v = acc[ti][tj][r];
                if constexpr (MODE == 0) {
                    int b = m >> 11, s = m & 2047;
                    int which = n >> 11, hd = n & 2047;           // uniform per block
                    if (which == 2) {
                        Vb[(size_t)m * 2048 + hd] = (__bf16)v;    // token-major
                    } else {
                        if (which == 0) v *= QS;                  // fold softmax scale
                        size_t idx = ((size_t)((b << 4) + (hd >> 7)) * 2048 + s) * 128
                                     + (hd & 127);
                        if (which == 0) Qb[idx] = (__bf16)v; else Kb[idx] = (__bf16)v;
                    }
                } else {
                    outF[(size_t)m * N + n] = v;
                }
            }
}

// ---------------------------------------------------------------- attention
// Unsplit: block owns 128 resident rows, sweeps all 2048 streamed rows in
// 32 dbuf'd 64-row tiles. Per-wave: 16 resident frags (64 VGPR), streamed
// half-tile -> 8 ds_read_b128 : 32 MFMA per iter. Grid 512. No atomics to
// global, no memset/recip/vscale kernels.
// Swizzle: 16 chunks of 16B per 256B row, content chunk cc = j ^ (row&7).

__launch_bounds__(256, 2)
__global__ void attn_l_k(const bf16_t* __restrict__ Qb, const bf16_t* __restrict__ Kb,
                         float* __restrict__ rl)
{
    __shared__ __align__(16) bf16_t lds[2][64 * 128];   // 2 x 16 KiB
    const int tid  = threadIdx.x;
    const int lane = tid & 63, wave = tid >> 6;
    const int quad = lane >> 4, l15 = lane & 15;
    const int qt = blockIdx.x, bh = blockIdx.y;
    const bf16_t* Qg = Qb + (size_t)bh * 2048 * 128 + (size_t)qt * 128 * 128;
    const bf16_t* Kg = Kb + (size_t)bh * 2048 * 128;
    const int wr0 = (wave >> 1) * 64;   // resident q rows
    const int wc0 = (wave & 1) * 32;    // streamed half-tile

    int srow[4], scc[4]; uint32_t soff[4];
#pragma unroll
    for (int r = 0; r < 4; ++r) {
        int s = r * 256 + wave * 64 + lane;
        srow[r] = s >> 4; int j = s & 15;
        scc[r] = j ^ (srow[r] & 7);
        soff[r] = (uint32_t)(r * 256 + wave * 64) * 16;
    }
    // stage resident Q (128 rows, 32 KiB) into lds[0..1]
#pragma unroll
    for (int r = 0; r < 4; ++r) {
        gll16(Qg + (size_t)srow[r] * 128 + scc[r] * 8, (char*)lds[0] + soff[r]);
        gll16(Qg + (size_t)(64 + srow[r]) * 128 + scc[r] * 8, (char*)lds[1] + soff[r]);
    }
    __syncthreads();
    bf16x8v qf[4][4];   // [kb][ti] : 64 VGPR, invariant over the sweep
#pragma unroll
    for (int kb = 0; kb < 4; ++kb)
#pragma unroll
        for (int t = 0; t < 4; ++t) {
            int m = wr0 + t * 16 + l15;   // 0..127
            qf[kb][t] = *reinterpret_cast<const bf16x8v*>(
                &lds[0][0] + (m * 16 + ((kb * 4 + quad) ^ (m & 7))) * 8);
        }
    __syncthreads();    // Q reads drained before K overwrites
#pragma unroll
    for (int r = 0; r < 4; ++r)   // prefetch K tile 0
        gll16(Kg + (size_t)srow[r] * 128 + scc[r] * 8, (char*)lds[0] + soff[r]);

    float lsum[4][4] = {};
    for (int it = 0; it < 32; ++it) {
        __syncthreads();   // K[it] staged; prior buf reads done
        const bf16_t* cb = lds[it & 1];
        if (it < 31) {
            char* tgt = (char*)lds[(it & 1) ^ 1];
#pragma unroll
            for (int r = 0; r < 4; ++r)
                gll16(Kg + (size_t)((it + 1) * 64 + srow[r]) * 128 + scc[r] * 8,
                      tgt + soff[r]);
        }
        f32x4v sc[4][2] = {};
#pragma unroll
        for (int kb = 0; kb < 4; ++kb) {
            int ccq = kb * 4 + quad;
            bf16x8v bv[2];
#pragma unroll
            for (int tj = 0; tj < 2; ++tj) {
                int n = wc0 + tj * 16 + l15;   // 0..63
                bv[tj] = *reinterpret_cast<const bf16x8v*>(
                    cb + (n * 16 + (ccq ^ (n & 7))) * 8);
            }
#pragma unroll
            for (int ti = 0; ti < 4; ++ti)
#pragma unroll
                for (int tj = 0; tj < 2; ++tj)
                    sc[ti][tj] = __builtin_amdgcn_mfma_f32_16x16x32_bf16(
                                     qf[kb][ti], bv[tj], sc[ti][tj], 0, 0, 0);
        }
#pragma unroll
        for (int ti = 0; ti < 4; ++ti)
#pragma unroll
            for (int r = 0; r < 4; ++r)
                lsum[ti][r] += __builtin_amdgcn_exp2f(sc[ti][0][r])
                             + __builtin_amdgcn_exp2f(sc[ti][1][r]);
    }
    // reduce across l15 (cols) then across wave pairs (streamed halves)
    __syncthreads();
    float* l_sh = (float*)lds[0];
    if (tid < 128) l_sh[tid] = 0.f;
    __syncthreads();
#pragma unroll
    for (int ti = 0; ti < 4; ++ti)
#pragma unroll
        for (int r = 0; r < 4; ++r) {
            float v = lsum[ti][r];
            v += __shfl_xor(v, 1); v += __shfl_xor(v, 2);
            v += __shfl_xor(v, 4); v += __shfl_xor(v, 8);
            if (l15 == 0) atomicAdd(&l_sh[wr0 + ti * 16 + quad * 4 + r], v);
        }
    __syncthreads();
    if (tid < 128)
        rl[(size_t)bh * 2048 + qt * 128 + tid] = 1.0f / l_sh[tid];
}

__launch_bounds__(256, 2)
__global__ void attn_cs_k(const bf16_t* __restrict__ Qb, const bf16_t* __restrict__ Kb,
                          const float* __restrict__ rl, bf16_t* __restrict__ Vb)
{
    __shared__ __align__(16) bf16_t lds[2][64 * 128];   // 2 x 16 KiB
    const int tid  = threadIdx.x;
    const int lane = tid & 63, wave = tid >> 6;
    const int quad = lane >> 4, l15 = lane & 15;
    const int kt = blockIdx.x, bh = blockIdx.y;
    const bf16_t* Kg = Kb + (size_t)bh * 2048 * 128 + (size_t)kt * 128 * 128;
    const bf16_t* Qg = Qb + (size_t)bh * 2048 * 128;
    const float* rlg = rl + (size_t)bh * 2048;
    const int wcK = (wave >> 1) * 64;   // resident k cols
    const int wq  = (wave & 1) * 32;    // streamed half-tile (q rows)

    int srow[4], scc[4]; uint32_t soff[4];
#pragma unroll
    for (int r = 0; r < 4; ++r) {
        int s = r * 256 + wave * 64 + lane;
        srow[r] = s >> 4; int j = s & 15;
        scc[r] = j ^ (srow[r] & 7);
        soff[r] = (uint32_t)(r * 256 + wave * 64) * 16;
    }
    // stage resident K (128 rows, 32 KiB)
#pragma unroll
    for (int r = 0; r < 4; ++r) {
        gll16(Kg + (size_t)srow[r] * 128 + scc[r] * 8, (char*)lds[0] + soff[r]);
        gll16(Kg + (size_t)(64 + srow[r]) * 128 + scc[r] * 8, (char*)lds[1] + soff[r]);
    }
    __syncthreads();
    bf16x8v kf[4][4];   // [kb][tk]
#pragma unroll
    for (int kb = 0; kb < 4; ++kb)
#pragma unroll
        for (int t = 0; t < 4; ++t) {
            int n = wcK + t * 16 + l15;   // 0..127
            kf[kb][t] = *reinterpret_cast<const bf16x8v*>(
                &lds[0][0] + (n * 16 + ((kb * 4 + quad) ^ (n & 7))) * 8);
        }
    __syncthreads();
#pragma unroll
    for (int r = 0; r < 4; ++r)   // prefetch Q tile 0
        gll16(Qg + (size_t)srow[r] * 128 + scc[r] * 8, (char*)lds[0] + soff[r]);

    float csum[4] = {};
    for (int it = 0; it < 32; ++it) {
        __syncthreads();
        const bf16_t* cb = lds[it & 1];
        if (it < 31) {
            char* tgt = (char*)lds[(it & 1) ^ 1];
#pragma unroll
            for (int r = 0; r < 4; ++r)
                gll16(Qg + (size_t)((it + 1) * 64 + srow[r]) * 128 + scc[r] * 8,
                      tgt + soff[r]);
        }
        f32x4v sc[2][4] = {};
#pragma unroll
        for (int kb = 0; kb < 4; ++kb) {
            int ccq = kb * 4 + quad;
            bf16x8v av[2];
#pragma unroll
            for (int ta = 0; ta < 2; ++ta) {
                int m = wq + ta * 16 + l15;   // 0..63 streamed q rows
                av[ta] = *reinterpret_cast<const bf16x8v*>(
                    cb + (m * 16 + (ccq ^ (m & 7))) * 8);
            }
#pragma unroll
            for (int ta = 0; ta < 2; ++ta)
#pragma unroll
                for (int tk = 0; tk < 4; ++tk)
                    sc[ta][tk] = __builtin_amdgcn_mfma_f32_16x16x32_bf16(
                                     av[ta], kf[kb][tk], sc[ta][tk], 0, 0, 0);
        }
#pragma unroll
        for (int ta = 0; ta < 2; ++ta) {
            f32x4v rlv = *reinterpret_cast<const f32x4v*>(
                rlg + it * 64 + wq + ta * 16 + quad * 4);
#pragma unroll
            for (int r = 0; r < 4; ++r)
#pragma unroll
                for (int tk = 0; tk < 4; ++tk)
                    csum[tk] += __builtin_amdgcn_exp2f(sc[ta][tk][r]) * rlv[r];
        }
    }
    // col-reduce across quads, then across wave pairs via LDS
    __syncthreads();
    float* cs_sh = (float*)lds[0];
    if (tid < 128) cs_sh[tid] = 0.f;
    __syncthreads();
#pragma unroll
    for (int tk = 0; tk < 4; ++tk) {
        float v = csum[tk];
        v += __shfl_xor(v, 16); v += __shfl_xor(v, 32);
        if (quad == 0) atomicAdd(&cs_sh[wcK + tk * 16 + l15], v);
    }
    __syncthreads();
    // fused: scale this block's disjoint 128x128 V patch in place
    int b = bh >> 4, h = bh & 15;
#pragma unroll
    for (int r = 0; r < 8; ++r) {
        int s = r * 256 + tid;
        int row = s >> 4, jc = s & 15;
        size_t off = ((size_t)(b * 2048 + kt * 128 + row)) * 2048 + h * 128 + jc * 8;
        float csv = cs_sh[row];
        bf16x8v vv = *reinterpret_cast<const bf16x8v*>(Vb + off);
        bf16x8v ov;
#pragma unroll
        for (int i = 0; i < 8; ++i) ov[i] = (__bf16)((float)vv[i] * csv);
        *reinterpret_cast<bf16x8v*>(Vb + off) = ov;
    }
}

// ---------------------------------------------------------------- launch
extern "C" void kernel_launch(void* const* d_in, const int* in_sizes, int n_in,
                              void* d_out, int out_size, void* d_ws, size_t ws_size,
                              hipStream_t stream) {
    (void)in_sizes; (void)n_in; (void)out_size; (void)ws_size;
    const float* x     = (const float*)d_in[0];
    const float* w_qkv = (const float*)d_in[1];
    const float* w_o   = (const float*)d_in[2];
    float* out = (float*)d_out;

    char* w = (char*)d_ws;
    auto alloc = [&](size_t bytes) {
        char* p = w; w += (bytes + 255) & ~(size_t)255; return p;
    };
    bf16_t* Xb    = (bf16_t*)alloc(4096ull * 2048 * 2);   // 16 MiB
    bf16_t* WqkvT = (bf16_t*)alloc(6144ull * 2048 * 2);   // 24 MiB
    bf16_t* WoT   = (bf16_t*)alloc(2048ull * 2048 * 2);   //  8 MiB
    bf16_t* Qb    = (bf16_t*)alloc(32ull * 2048 * 128 * 2); // 16 MiB [bh][s][d]
    bf16_t* Kb    = (bf16_t*)alloc(32ull * 2048 * 128 * 2);
    bf16_t* Vb    = (bf16_t*)alloc(4096ull * 2048 * 2);   // token-major
    float*  rlb   = (float*)alloc(32ull * 2048 * 4);      // 1/l (plain stores)

    conv_x_k <<<8192, 256, 0, stream>>>(x, Xb);
    conv_wT_k<<<dim3(192, 32), 256, 0, stream>>>(w_qkv, WqkvT, 2048, 6144);
    conv_wT_k<<<dim3(64, 32),  256, 0, stream>>>(w_o,   WoT,   2048, 2048);

    gemm_bt_k<0, 6144, 2048><<<dim3(48, 32), 256, 0, stream>>>(
        Xb, WqkvT, nullptr, Qb, Kb, Vb);

    attn_l_k <<<dim3(16, 32), 256, 0, stream>>>(Qb, Kb, rlb);
    attn_cs_k<<<dim3(16, 32), 256, 0, stream>>>(Qb, Kb, rlb, Vb);

    gemm_bt_k<1, 2048, 2048><<<dim3(16, 32), 256, 0, stream>>>(
        Vb, WoT, out, nullptr, nullptr, nullptr);
}